// Round 1
// baseline (1121.284 us; speedup 1.0000x reference)
//
#include <hip/hip_runtime.h>

#define CC 64
#define HH 256
#define WW 256
#define HW (HH * WW)

// Wcomb[i][k][c][o] = sum_c2 Wfuse[o, i*64+c2] * Wd[i, c2, c, ky, kx]
__global__ void wcomb_kernel(const float* __restrict__ Wd,
                             const float* __restrict__ Wfuse,
                             float* __restrict__ Wcomb) {
    int idx = blockIdx.x * blockDim.x + threadIdx.x;
    if (idx >= 3 * 9 * 64 * 64) return;
    int o = idx & 63;
    int c = (idx >> 6) & 63;
    int ik = idx >> 12;          // 0..26
    int k = ik % 9;
    int i = ik / 9;
    const float* wf = Wfuse + o * 192 + i * 64;          // c2 stride 1
    const float* wd = Wd + ((size_t)(i * 64) * 64 + c) * 9 + k; // c2 stride 576
    float s = 0.f;
    for (int c2 = 0; c2 < 64; ++c2)
        s = fmaf(wf[c2], wd[(size_t)c2 * 576], s);
    Wcomb[idx] = s;   // idx == ((i*9+k)*64 + c)*64 + o
}

// One wave (64 lanes) = 64 consecutive pixels of one row; lane = w.
// Phase 1: fused 3x3 offset conv (54 channels). Phase 2: 27 deformable taps,
// bilinear sample per channel, 64x1728 matvec with precombined weights.
__launch_bounds__(256, 2)
__global__ void mspadc_main(const float* __restrict__ x,
                            const float* __restrict__ Woff,
                            const float* __restrict__ boff,
                            const float* __restrict__ Wcomb,
                            float* __restrict__ out) {
    const int tid = threadIdx.x;
    const int lane = tid & 63;
    const int gwave = blockIdx.x * 4 + (tid >> 6);   // 0..2047
    const int w = ((gwave & 3) << 6) + lane;         // 4 w-tiles of 64
    const int h = (gwave >> 2) & 255;
    const int b = gwave >> 10;

    const float* xb = x + (size_t)b * CC * HW;

    // ---- Phase 1: offsets off[n] = boff[n] + conv3x3(x, Woff)[n] ----
    float off[54];
#pragma unroll
    for (int n = 0; n < 54; ++n) off[n] = boff[n];

    {
        const float* xc = xb;
        for (int c = 0; c < CC; ++c, xc += HW) {
            float xv[9];
#pragma unroll
            for (int t = 0; t < 9; ++t) {
                const int yy = h + (t / 3) - 1;
                const int xx = w + (t % 3) - 1;
                const bool v = (yy >= 0) && (yy < HH) && (xx >= 0) && (xx < WW);
                xv[t] = v ? xc[yy * WW + xx] : 0.f;
            }
            const float* wp = Woff + c * 9;   // + n*576 + t
#pragma unroll
            for (int n = 0; n < 54; ++n) {
                float a = off[n];
#pragma unroll
                for (int t = 0; t < 9; ++t)
                    a = fmaf(wp[n * 576 + t], xv[t], a);
                off[n] = a;
            }
        }
    }

    // ---- Phase 2: deformable sampling + fused matvec ----
    float acc[64];
#pragma unroll
    for (int o = 0; o < 64; ++o) acc[o] = 0.f;

    const float fh = (float)h, fw = (float)w;

#pragma unroll
    for (int i = 0; i < 3; ++i) {
        const int d = 1 << i;   // 1, 2, 4
#pragma unroll
        for (int k = 0; k < 9; ++k) {
            const float dy = off[i * 18 + k * 2 + 0];
            const float dx = off[i * 18 + k * 2 + 1];
            const float ys = fh + (float)((k / 3 - 1) * d) + dy;
            const float xs = fw + (float)((k % 3 - 1) * d) + dx;
            const float y0f = floorf(ys), x0f = floorf(xs);
            const float wy1 = ys - y0f, wx1 = xs - x0f;
            const float wy0 = 1.f - wy1, wx0 = 1.f - wx1;
            const float y1f = y0f + 1.f, x1f = x0f + 1.f;
            const float vy0 = (y0f >= 0.f && y0f <= 255.f) ? 1.f : 0.f;
            const float vy1 = (y1f >= 0.f && y1f <= 255.f) ? 1.f : 0.f;
            const float vx0 = (x0f >= 0.f && x0f <= 255.f) ? 1.f : 0.f;
            const float vx1 = (x1f >= 0.f && x1f <= 255.f) ? 1.f : 0.f;
            const float c00 = wy0 * wx0 * vy0 * vx0;
            const float c01 = wy0 * wx1 * vy0 * vx1;
            const float c10 = wy1 * wx0 * vy1 * vx0;
            const float c11 = wy1 * wx1 * vy1 * vx1;
            const int y0 = (int)fminf(fmaxf(y0f, 0.f), 255.f);
            const int y1 = (int)fminf(fmaxf(y1f, 0.f), 255.f);
            const int x0 = (int)fminf(fmaxf(x0f, 0.f), 255.f);
            const int x1 = (int)fminf(fmaxf(x1f, 0.f), 255.f);
            const int o00 = y0 * WW + x0, o01 = y0 * WW + x1;
            const int o10 = y1 * WW + x0, o11 = y1 * WW + x1;

            const float* pc = xb;
            const float* wc = Wcomb + (size_t)(i * 9 + k) * 64 * 64;
            for (int c = 0; c < CC; ++c, pc += HW, wc += 64) {
                float s = pc[o00] * c00;
                s = fmaf(pc[o01], c01, s);
                s = fmaf(pc[o10], c10, s);
                s = fmaf(pc[o11], c11, s);
#pragma unroll
                for (int o = 0; o < 64; ++o)
                    acc[o] = fmaf(wc[o], s, acc[o]);
            }
        }
    }

    float* op = out + (size_t)b * CC * HW + (size_t)h * WW + w;
#pragma unroll
    for (int o = 0; o < 64; ++o)
        op[(size_t)o * HW] = acc[o];
}

extern "C" void kernel_launch(void* const* d_in, const int* in_sizes, int n_in,
                              void* d_out, int out_size, void* d_ws, size_t ws_size,
                              hipStream_t stream) {
    const float* x     = (const float*)d_in[0];
    const float* Woff  = (const float*)d_in[1];
    const float* boff  = (const float*)d_in[2];
    const float* Wd    = (const float*)d_in[3];
    const float* Wfuse = (const float*)d_in[4];
    float* out = (float*)d_out;
    float* Wcomb = (float*)d_ws;   // 3*9*64*64 floats = 442,368 B

    wcomb_kernel<<<432, 256, 0, stream>>>(Wd, Wfuse, Wcomb);
    mspadc_main<<<512, 256, 0, stream>>>(x, Woff, boff, Wcomb, out);
}